// Round 6
// baseline (59.766 us; speedup 1.0000x reference)
//
#include <hip/hip_runtime.h>

// RotMat forward: 511 rounds of 256 disjoint Givens rotations on rows of a
// [512, 1024] fp32 matrix (round-robin tournament schedule).
//
// Position-space formulation: position k pairs with 511-k every round; between
// rounds values shift cyclically (pair-space: L[k]<-L[k-1], H[k]<-H[k+1] with
// end specials). After 511 rounds the permutation is identity.
//
// Ladder: R0 177us (no prefetch, ~900cy/round HBM latency exposed).
// R1 75us (reg ring; regalloc collapsed depth to ~6). R3 60us (DPP shifts
// replace ds_bpermute). R4 58.7us (global_load_lds double-buffered chunks,
// counted vmcnt + raw s_barrier) -- no change vs R3: global fetch is NOT the
// stall. R5: full-chunk register preload of coefficients (32x ds_read_b128
// issued back-to-back at chunk top, sched_barrier(0)-pinned) so ds_read->use
// distance is hundreds of cycles regardless of compiler scheduling. Tests the
// "per-round LDS latency exposed" hypothesis; VGPR cost (~+128) is free at
// 1 block/CU (LDS-capped).

#define N_COLS      1024
#define PAIRS       256
#define CHUNK       16                 // rounds per chunk
#define CHUNK_BYTES (CHUNK * 2048)     // 32 KB (2KB per round)

// Table layout (plane form): float2 index = r*256 + plane*128 + lane*2 + slot
// where pair k -> plane=(k>>1)&1, lane=k>>2, slot=k&1. Lane l's round-r data:
// planeA float4 = pairs 4l,4l+1 at f4 idx r*128 + l; planeB = pairs 4l+2,4l+3
// at r*128 + 64 + l. Both ds_read_b128 stride-16B across lanes (conflict-free,
// SQ_LDS_BANK_CONFLICT=0 confirmed in R4).
__global__ __launch_bounds__(256) void rotmat_setup(const float* __restrict__ thetas,
                                                    float2* __restrict__ cs) {
    const int r = blockIdx.x;   // 0..510
    const int k = threadIdx.x;  // 0..255 (pair index)
    int pu = (k == 0) ? 0 : ((k - 1 - r + 1022) % 511) + 1;
    int pv = ((510 - k - r + 1022) % 511) + 1;
    int i = min(pu, pv), j = max(pu, pv);
    int t = i * 511 - (i * (i - 1)) / 2 + (j - i - 1);
    float s, c;
    sincosf(thetas[t], &s, &c);
    float sp = (pu < pv) ? s : -s;
    int plane = (k >> 1) & 1, ln = k >> 2, slot = k & 1;
    cs[r * 256 + plane * 128 + ln * 2 + slot] = make_float2(c, sp);
}

// DPP wave-shift helpers (gfx9 lineage). WAVE_SHR1 0x138: lane i <- i-1, lane0
// keeps `old`. WAVE_SHL1 0x130: lane i <- i+1, lane63 keeps `old`.
__device__ __forceinline__ float dpp_shr1(float old, float src) {
    return __int_as_float(__builtin_amdgcn_update_dpp(
        __float_as_int(old), __float_as_int(src), 0x138, 0xF, 0xF, false));
}
__device__ __forceinline__ float dpp_shl1(float old, float src) {
    return __int_as_float(__builtin_amdgcn_update_dpp(
        __float_as_int(old), __float_as_int(src), 0x130, 0xF, 0xF, false));
}

__device__ __forceinline__ void glds16(const void* g, void* l) {
    __builtin_amdgcn_global_load_lds(
        (const __attribute__((address_space(1))) void*)g,
        (__attribute__((address_space(3))) void*)l, 16, 0, 0);
}

#define ROT(mi, C, S)                                   \
    {                                                   \
        float L = lo[mi], H = hi[mi];                   \
        lo[mi] = fmaf((C), L, -(S) * H);                \
        hi[mi] = fmaf((C), H, (S) * L);                 \
    }

#define SHIFT()                                                   \
    {                                                             \
        float nlo0 = dpp_shr1(lo[0], lo[3]);                      \
        float nhi3 = dpp_shl1(lo[3], hi[0]);                      \
        float nlo1 = is0 ? hi[0] : lo[0];                         \
        lo[3] = lo[2]; lo[2] = lo[1]; lo[1] = nlo1; lo[0] = nlo0; \
        hi[0] = hi[1]; hi[1] = hi[2]; hi[2] = hi[3]; hi[3] = nhi3;\
    }

#define ROUND(AA, BB)            \
    ROT(0, (AA).x, (AA).y)       \
    ROT(1, (AA).z, (AA).w)       \
    ROT(2, (BB).x, (BB).y)       \
    ROT(3, (BB).z, (BB).w)       \
    SHIFT()

// Stage chunk cix into buffer bix: this wave covers bytes [wave*8K, wave*8K+8K)
// of the 32KB chunk = 8 x 1KB global_load_lds (global src per-lane, LDS dst
// wave-uniform; HW adds lane*16).
#define STAGE(cix, bix)                                              \
    {                                                                \
        const char* g_ = gsrc + (size_t)(cix)*CHUNK_BYTES;           \
        char* l_ = lb + (bix)*CHUNK_BYTES;                           \
        _Pragma("unroll")                                            \
        for (int j = 0; j < 8; ++j)                                  \
            glds16(g_ + j * 1024, l_ + j * 1024);                    \
    }

// Compute NR rounds of chunk in buffer bix. Full-chunk preload: all 32
// ds_read_b128 issued up front (in-order issue ~100cy), then pure-VALU rounds.
// sched_barrier(0) pins the reads above the rounds.
#define BODY(bix, NR)                                                          \
    {                                                                          \
        float4 A[CHUNK], B[CHUNK];                                             \
        _Pragma("unroll")                                                      \
        for (int u = 0; u < CHUNK; ++u) {                                      \
            A[u] = tab[bix][u][0][lane];                                       \
            B[u] = tab[bix][u][1][lane];                                       \
        }                                                                      \
        __builtin_amdgcn_sched_barrier(0);                                     \
        _Pragma("unroll")                                                      \
        for (int u = 0; u < (NR); ++u) {                                       \
            ROUND(A[u], B[u])                                                  \
        }                                                                      \
    }

#define WAITV(n) asm volatile("s_waitcnt vmcnt(" #n ")" ::: "memory")
#define BAR()                               \
    __builtin_amdgcn_s_barrier();           \
    __builtin_amdgcn_sched_barrier(0)

template <bool TAB>
__global__ __launch_bounds__(256, 1) void rotmat_main(const float* __restrict__ x,
                                                      const float* __restrict__ thetas,
                                                      const float2* __restrict__ cs,
                                                      float* __restrict__ out) {
    __shared__ float4 tab[2][CHUNK][2][64];  // [buf][round][plane][lane] = 64KB

    const int lane = threadIdx.x & 63;
    const int wave = threadIdx.x >> 6;
    const int col  = (blockIdx.x << 2) + wave;  // one column per wave
    const int k0   = lane << 2;                 // first pair index of this lane
    const bool is0 = (lane == 0);

    float lo[4], hi[4];
#pragma unroll
    for (int m = 0; m < 4; ++m) {
        lo[m] = x[(k0 + m) * N_COLS + col];
        hi[m] = x[(511 - k0 - m) * N_COLS + col];
    }

    if constexpr (TAB) {
        const char* gsrc = (const char*)cs + (size_t)wave * 8192 + (size_t)lane * 16;
        char* lb = (char*)(&tab[0][0][0][0]) + wave * 8192;

        // Prologue: stage chunks 0,1; wait for 0 (mine); sync all stagers.
        STAGE(0, 0)
        STAGE(1, 1)
        WAITV(8);
        BAR();

        // Chunks 0..29. During chunk c: buf[c&1] in use, buf[(c+1)&1] holds
        // c+1. After compute: barrier (reads done), stage c+2 over c's buffer,
        // vmcnt(8) (c+1 fully arrived), barrier.
        for (int t2 = 0; t2 < 15; ++t2) {
            const int c0 = 2 * t2;
            BODY(0, CHUNK)
            BAR();
            STAGE(c0 + 2, 0)
            WAITV(8);
            BAR();
            BODY(1, CHUNK)
            BAR();
            STAGE(c0 + 3, 1)
            WAITV(8);
            BAR();
        }
        // Chunk 30 (buf0); then drain for chunk 31 (staged at t2=14).
        BODY(0, CHUNK)
        WAITV(0);
        BAR();
        // Chunk 31: rounds 496..510 (15 real rounds; round 511 is pad).
        BODY(1, 15)
    } else {
        // Fallback: compute schedule + sincos inline (no workspace table).
        int pu[4], pv[4];
#pragma unroll
        for (int m = 0; m < 4; ++m) {
            pu[m] = (k0 + m == 0) ? 0 : (k0 + m);
            pv[m] = 511 - (k0 + m);
        }
        for (int r = 0; r < 511; ++r) {
#pragma unroll
            for (int m = 0; m < 4; ++m) {
                int i = min(pu[m], pv[m]), j = max(pu[m], pv[m]);
                int t = i * 511 - (i * (i - 1)) / 2 + (j - i - 1);
                float s, c;
                sincosf(thetas[t], &s, &c);
                float sp = (pu[m] < pv[m]) ? s : -s;
                ROT(m, c, sp)
            }
            SHIFT()
#pragma unroll
            for (int m = 0; m < 4; ++m) {
                pu[m] = (k0 + m == 0) ? 0 : ((pu[m] == 1) ? 511 : pu[m] - 1);
                pv[m] = (pv[m] == 1) ? 511 : pv[m] - 1;
            }
        }
    }

    // After 511 shifts the position->row permutation is identity.
#pragma unroll
    for (int m = 0; m < 4; ++m) {
        out[(k0 + m) * N_COLS + col]       = lo[m];
        out[(511 - k0 - m) * N_COLS + col] = hi[m];
    }
}

extern "C" void kernel_launch(void* const* d_in, const int* in_sizes, int n_in,
                              void* d_out, int out_size, void* d_ws, size_t ws_size,
                              hipStream_t stream) {
    const float* x  = (const float*)d_in[0];
    const float* th = (const float*)d_in[1];
    float* out      = (float*)d_out;

    // Table: 512 rounds padded (chunk 31 stages pad round 511; never consumed).
    const size_t need = (size_t)512 * PAIRS * sizeof(float2);  // 1 MiB
    if (ws_size >= need) {
        float2* cs = (float2*)d_ws;
        rotmat_setup<<<511, PAIRS, 0, stream>>>(th, cs);
        rotmat_main<true><<<N_COLS / 4, 256, 0, stream>>>(x, th, cs, out);
    } else {
        rotmat_main<false><<<N_COLS / 4, 256, 0, stream>>>(x, th, nullptr, out);
    }
}

// Round 7
// 52.084 us; speedup vs baseline: 1.1475x; 1.1475x over previous
//
#include <hip/hip_runtime.h>

// RotMat forward: 511 rounds of 256 disjoint Givens rotations on rows of a
// [512, 1024] fp32 matrix (round-robin tournament schedule).
//
// Position-space formulation: position k pairs with 511-k every round; between
// rounds values shift cyclically (pair-space: L[k]<-L[k-1], H[k]<-H[k+1] with
// end specials). After 511 rounds the permutation is identity.
//
// Ladder: R0 177us (no prefetch). R1 75us (reg ring; regalloc collapsed it).
// R3 60us (DPP shifts replace ds_bpermute). R4 58.7us (global_load_lds double
// buffer): global fetch not the stall. R5 59.8us, VGPR=88: HIP-level
// full-chunk preload NEVER MATERIALIZED (128 VGPRs of preload can't fit in
// 88) -- compiler re-sank the ds_reads to their uses, exposing ~120cy+ LDS
// latency per round. R6: preload forced at ISA level -- 16x inline-asm
// ds_read_b128 with "=v" outputs (named vars; architecturally live, volatile,
// cannot be sunk), then s_waitcnt lgkmcnt(0) + sched_barrier(0) (rule #18).
// CHUNK 16->8 so pinned coeffs = 64 VGPR. Verification signal: VGPR ~110+.

#define N_COLS      1024
#define PAIRS       256
#define CHUNK       8                  // rounds per chunk
#define CHUNK_BYTES (CHUNK * 2048)     // 16 KB (2KB per round)

typedef __attribute__((ext_vector_type(4))) float f32x4;

// Table layout (plane form): float2 index = r*256 + plane*128 + lane*2 + slot
// where pair k -> plane=(k>>1)&1, lane=k>>2, slot=k&1. Lane l's round-r data:
// planeA f32x4 = pairs 4l,4l+1 at byte r*2048 + lane*16; planeB = pairs
// 4l+2,4l+3 at r*2048 + 1024 + lane*16. Stride-16B across lanes: conflict-free
// (SQ_LDS_BANK_CONFLICT=0 confirmed R4/R5).
__global__ __launch_bounds__(256) void rotmat_setup(const float* __restrict__ thetas,
                                                    float2* __restrict__ cs) {
    const int r = blockIdx.x;   // 0..510
    const int k = threadIdx.x;  // 0..255 (pair index)
    int pu = (k == 0) ? 0 : ((k - 1 - r + 1022) % 511) + 1;
    int pv = ((510 - k - r + 1022) % 511) + 1;
    int i = min(pu, pv), j = max(pu, pv);
    int t = i * 511 - (i * (i - 1)) / 2 + (j - i - 1);
    float s, c;
    sincosf(thetas[t], &s, &c);
    float sp = (pu < pv) ? s : -s;
    int plane = (k >> 1) & 1, ln = k >> 2, slot = k & 1;
    cs[r * 256 + plane * 128 + ln * 2 + slot] = make_float2(c, sp);
}

// DPP wave-shift helpers (gfx9 lineage). WAVE_SHR1 0x138: lane i <- i-1, lane0
// keeps `old`. WAVE_SHL1 0x130: lane i <- i+1, lane63 keeps `old`.
__device__ __forceinline__ float dpp_shr1(float old, float src) {
    return __int_as_float(__builtin_amdgcn_update_dpp(
        __float_as_int(old), __float_as_int(src), 0x138, 0xF, 0xF, false));
}
__device__ __forceinline__ float dpp_shl1(float old, float src) {
    return __int_as_float(__builtin_amdgcn_update_dpp(
        __float_as_int(old), __float_as_int(src), 0x130, 0xF, 0xF, false));
}

__device__ __forceinline__ void glds16(const void* g, void* l) {
    __builtin_amdgcn_global_load_lds(
        (const __attribute__((address_space(1))) void*)g,
        (__attribute__((address_space(3))) void*)l, 16, 0, 0);
}

#define ROT(mi, C, S)                                   \
    {                                                   \
        float L = lo[mi], H = hi[mi];                   \
        lo[mi] = fmaf((C), L, -(S) * H);                \
        hi[mi] = fmaf((C), H, (S) * L);                 \
    }

#define SHIFT()                                                   \
    {                                                             \
        float nlo0 = dpp_shr1(lo[0], lo[3]);                      \
        float nhi3 = dpp_shl1(lo[3], hi[0]);                      \
        float nlo1 = is0 ? hi[0] : lo[0];                         \
        lo[3] = lo[2]; lo[2] = lo[1]; lo[1] = nlo1; lo[0] = nlo0; \
        hi[0] = hi[1]; hi[1] = hi[2]; hi[2] = hi[3]; hi[3] = nhi3;\
    }

#define ROUND(AA, BB)            \
    ROT(0, (AA).x, (AA).y)       \
    ROT(1, (AA).z, (AA).w)       \
    ROT(2, (BB).x, (BB).y)       \
    ROT(3, (BB).z, (BB).w)       \
    SHIFT()

// Inline-asm ds_read_b128: output registers are architecturally live until
// consumed; volatile -> cannot be sunk, duplicated, or rematerialized.
#define DSR(dst, imm)                                          \
    asm volatile("ds_read_b128 %0, %1 offset:%c2"              \
                 : "=v"(dst) : "v"(lds_addr), "i"(imm))

// Compute NR (8 or 7) rounds of the chunk at LDS byte base BOFF (0 or 16384).
// 16 pinned preloads -> one lgkmcnt(0) -> sched_barrier(0) -> pure-VALU rounds.
#define BODY(BOFF, NR)                                                        \
    {                                                                         \
        f32x4 a0, a1, a2, a3, a4, a5, a6, a7;                                 \
        f32x4 b0, b1, b2, b3, b4, b5, b6, b7;                                 \
        DSR(a0, (BOFF) + 0 * 2048); DSR(b0, (BOFF) + 0 * 2048 + 1024);        \
        DSR(a1, (BOFF) + 1 * 2048); DSR(b1, (BOFF) + 1 * 2048 + 1024);        \
        DSR(a2, (BOFF) + 2 * 2048); DSR(b2, (BOFF) + 2 * 2048 + 1024);        \
        DSR(a3, (BOFF) + 3 * 2048); DSR(b3, (BOFF) + 3 * 2048 + 1024);        \
        DSR(a4, (BOFF) + 4 * 2048); DSR(b4, (BOFF) + 4 * 2048 + 1024);        \
        DSR(a5, (BOFF) + 5 * 2048); DSR(b5, (BOFF) + 5 * 2048 + 1024);        \
        DSR(a6, (BOFF) + 6 * 2048); DSR(b6, (BOFF) + 6 * 2048 + 1024);        \
        DSR(a7, (BOFF) + 7 * 2048); DSR(b7, (BOFF) + 7 * 2048 + 1024);        \
        asm volatile("s_waitcnt lgkmcnt(0)" ::: "memory");                    \
        __builtin_amdgcn_sched_barrier(0);                                    \
        ROUND(a0, b0)                                                         \
        ROUND(a1, b1)                                                         \
        ROUND(a2, b2)                                                         \
        ROUND(a3, b3)                                                         \
        ROUND(a4, b4)                                                         \
        ROUND(a5, b5)                                                         \
        ROUND(a6, b6)                                                         \
        if ((NR) == 8) { ROUND(a7, b7) }                                      \
    }

// Stage chunk cix into buffer bix: this wave covers bytes [wave*4K, wave*4K+4K)
// of the 16KB chunk = 4 x 1KB global_load_lds.
#define STAGE(cix, bix)                                              \
    {                                                                \
        const char* g_ = gsrc + (size_t)(cix)*CHUNK_BYTES;           \
        char* l_ = lb + (bix)*CHUNK_BYTES;                           \
        _Pragma("unroll")                                            \
        for (int j = 0; j < 4; ++j)                                  \
            glds16(g_ + j * 1024, l_ + j * 1024);                    \
    }

#define WAITV(n) asm volatile("s_waitcnt vmcnt(" #n ")" ::: "memory")
#define BAR()                               \
    __builtin_amdgcn_s_barrier();           \
    __builtin_amdgcn_sched_barrier(0)

template <bool TAB>
__global__ __launch_bounds__(256, 1) void rotmat_main(const float* __restrict__ x,
                                                      const float* __restrict__ thetas,
                                                      const float2* __restrict__ cs,
                                                      float* __restrict__ out) {
    __shared__ f32x4 tab[2][CHUNK][2][64];  // [buf][round][plane][lane] = 32KB

    const int lane = threadIdx.x & 63;
    const int wave = threadIdx.x >> 6;
    const int col  = (blockIdx.x << 2) + wave;  // one column per wave
    const int k0   = lane << 2;                 // first pair index of this lane
    const bool is0 = (lane == 0);

    float lo[4], hi[4];
#pragma unroll
    for (int m = 0; m < 4; ++m) {
        lo[m] = x[(k0 + m) * N_COLS + col];
        hi[m] = x[(511 - k0 - m) * N_COLS + col];
    }

    if constexpr (TAB) {
        const char* gsrc = (const char*)cs + (size_t)wave * 4096 + (size_t)lane * 16;
        char* lb = (char*)(&tab[0][0][0][0]) + wave * 4096;
        unsigned lds_addr;
        {
            auto p3 = (__attribute__((address_space(3))) char*)(&tab[0][0][0][0]);
            lds_addr = (unsigned)(size_t)p3 + (unsigned)(lane * 16);
        }

        // Prologue: stage chunks 0,1; wait chunk 0 (and x loads); sync.
        STAGE(0, 0)
        STAGE(1, 1)
        WAITV(4);
        BAR();

        // 64 chunks of 8 rounds (512 incl. 1 pad round). Iteration t2 computes
        // chunks 2t2 (buf0), 2t2+1 (buf1); stages 2t2+2, 2t2+3. After compute:
        // barrier (asm reads already drained by lgkmcnt inside BODY), stage
        // over the just-used buffer, vmcnt(4) (previous stage arrived), barrier.
        for (int t2 = 0; t2 < 31; ++t2) {
            BODY(0, 8)
            BAR();
            STAGE(2 * t2 + 2, 0)
            WAITV(4);
            BAR();
            BODY(16384, 8)
            BAR();
            STAGE(2 * t2 + 3, 1)
            WAITV(4);
            BAR();
        }
        // Chunk 62 (buf0); drain for chunk 63 (staged at t2=30).
        BODY(0, 8)
        WAITV(0);
        BAR();
        // Chunk 63: rounds 504..510 (7 real rounds; round 511 is pad).
        BODY(16384, 7)
    } else {
        // Fallback: compute schedule + sincos inline (no workspace table).
        int pu[4], pv[4];
#pragma unroll
        for (int m = 0; m < 4; ++m) {
            pu[m] = (k0 + m == 0) ? 0 : (k0 + m);
            pv[m] = 511 - (k0 + m);
        }
        for (int r = 0; r < 511; ++r) {
#pragma unroll
            for (int m = 0; m < 4; ++m) {
                int i = min(pu[m], pv[m]), j = max(pu[m], pv[m]);
                int t = i * 511 - (i * (i - 1)) / 2 + (j - i - 1);
                float s, c;
                sincosf(thetas[t], &s, &c);
                float sp = (pu[m] < pv[m]) ? s : -s;
                ROT(m, c, sp)
            }
            SHIFT()
#pragma unroll
            for (int m = 0; m < 4; ++m) {
                pu[m] = (k0 + m == 0) ? 0 : ((pu[m] == 1) ? 511 : pu[m] - 1);
                pv[m] = (pv[m] == 1) ? 511 : pv[m] - 1;
            }
        }
    }

    // After 511 shifts the position->row permutation is identity.
#pragma unroll
    for (int m = 0; m < 4; ++m) {
        out[(k0 + m) * N_COLS + col]       = lo[m];
        out[(511 - k0 - m) * N_COLS + col] = hi[m];
    }
}

extern "C" void kernel_launch(void* const* d_in, const int* in_sizes, int n_in,
                              void* d_out, int out_size, void* d_ws, size_t ws_size,
                              hipStream_t stream) {
    const float* x  = (const float*)d_in[0];
    const float* th = (const float*)d_in[1];
    float* out      = (float*)d_out;

    // Table: 512 rounds padded (chunk 63 stages pad round 511; never consumed).
    const size_t need = (size_t)512 * PAIRS * sizeof(float2);  // 1 MiB
    if (ws_size >= need) {
        float2* cs = (float2*)d_ws;
        rotmat_setup<<<511, PAIRS, 0, stream>>>(th, cs);
        rotmat_main<true><<<N_COLS / 4, 256, 0, stream>>>(x, th, cs, out);
    } else {
        rotmat_main<false><<<N_COLS / 4, 256, 0, stream>>>(x, th, nullptr, out);
    }
}

// Round 8
// 50.503 us; speedup vs baseline: 1.1834x; 1.0313x over previous
//
#include <hip/hip_runtime.h>

// RotMat forward: 511 rounds of 256 disjoint Givens rotations on rows of a
// [512, 1024] fp32 matrix (round-robin tournament schedule).
//
// Position-space formulation: position k pairs with 511-k every round; between
// rounds values shift cyclically (pair-space: L[k]<-L[k-1], H[k]<-H[k+1] with
// end specials). After 511 rounds the permutation is identity.
//
// Ladder: R0 177us. R1 75us (reg ring; regalloc collapsed it). R3 60us (DPP
// shifts). R4 58.7us (global_load_lds dbuf; global fetch not the stall).
// R5 59.8us (HIP-level preload never materialized). R6 52us (ISA-pinned
// ds_read preload, single lgkmcnt(0) drain): a 2-phase stall -- all 16 reads
// drain serially (~LDS throughput shared by 4 waves + latency) before any
// VALU. R7: counted per-round lgkmcnt (DS ops complete in order): round u
// waits lgkmcnt(14-2u), so reads 2..15 drain UNDER rounds 0..6's VALU.
// sched_barrier(0) after each wait (rule #18: compiler hoists register-only
// VALU past inline-asm waitcnt otherwise).

#define N_COLS      1024
#define PAIRS       256
#define CHUNK       8                  // rounds per chunk
#define CHUNK_BYTES (CHUNK * 2048)     // 16 KB (2KB per round)

typedef __attribute__((ext_vector_type(4))) float f32x4;

// Table layout (plane form): float2 index = r*256 + plane*128 + lane*2 + slot
// where pair k -> plane=(k>>1)&1, lane=k>>2, slot=k&1. Lane l's round-r data:
// planeA f32x4 = pairs 4l,4l+1 at byte r*2048 + lane*16; planeB = pairs
// 4l+2,4l+3 at r*2048 + 1024 + lane*16. Stride-16B across lanes: conflict-free
// (SQ_LDS_BANK_CONFLICT=0 confirmed R4-R6).
__global__ __launch_bounds__(256) void rotmat_setup(const float* __restrict__ thetas,
                                                    float2* __restrict__ cs) {
    const int r = blockIdx.x;   // 0..510
    const int k = threadIdx.x;  // 0..255 (pair index)
    int pu = (k == 0) ? 0 : ((k - 1 - r + 1022) % 511) + 1;
    int pv = ((510 - k - r + 1022) % 511) + 1;
    int i = min(pu, pv), j = max(pu, pv);
    int t = i * 511 - (i * (i - 1)) / 2 + (j - i - 1);
    float s, c;
    sincosf(thetas[t], &s, &c);
    float sp = (pu < pv) ? s : -s;
    int plane = (k >> 1) & 1, ln = k >> 2, slot = k & 1;
    cs[r * 256 + plane * 128 + ln * 2 + slot] = make_float2(c, sp);
}

// DPP wave-shift helpers (gfx9 lineage). WAVE_SHR1 0x138: lane i <- i-1, lane0
// keeps `old`. WAVE_SHL1 0x130: lane i <- i+1, lane63 keeps `old`.
__device__ __forceinline__ float dpp_shr1(float old, float src) {
    return __int_as_float(__builtin_amdgcn_update_dpp(
        __float_as_int(old), __float_as_int(src), 0x138, 0xF, 0xF, false));
}
__device__ __forceinline__ float dpp_shl1(float old, float src) {
    return __int_as_float(__builtin_amdgcn_update_dpp(
        __float_as_int(old), __float_as_int(src), 0x130, 0xF, 0xF, false));
}

__device__ __forceinline__ void glds16(const void* g, void* l) {
    __builtin_amdgcn_global_load_lds(
        (const __attribute__((address_space(1))) void*)g,
        (__attribute__((address_space(3))) void*)l, 16, 0, 0);
}

#define ROT(mi, C, S)                                   \
    {                                                   \
        float L = lo[mi], H = hi[mi];                   \
        lo[mi] = fmaf((C), L, -(S) * H);                \
        hi[mi] = fmaf((C), H, (S) * L);                 \
    }

#define SHIFT()                                                   \
    {                                                             \
        float nlo0 = dpp_shr1(lo[0], lo[3]);                      \
        float nhi3 = dpp_shl1(lo[3], hi[0]);                      \
        float nlo1 = is0 ? hi[0] : lo[0];                         \
        lo[3] = lo[2]; lo[2] = lo[1]; lo[1] = nlo1; lo[0] = nlo0; \
        hi[0] = hi[1]; hi[1] = hi[2]; hi[2] = hi[3]; hi[3] = nhi3;\
    }

#define ROUND(AA, BB)            \
    ROT(0, (AA).x, (AA).y)       \
    ROT(1, (AA).z, (AA).w)       \
    ROT(2, (BB).x, (BB).y)       \
    ROT(3, (BB).z, (BB).w)       \
    SHIFT()

// Inline-asm ds_read_b128: outputs architecturally live, volatile -> cannot be
// sunk/rematerialized by the scheduler or regalloc.
#define DSR(dst, imm)                                          \
    asm volatile("ds_read_b128 %0, %1 offset:%c2"              \
                 : "=v"(dst) : "v"(lds_addr), "i"(imm))

#define WAITL(n)                                                   \
    asm volatile("s_waitcnt lgkmcnt(" #n ")" ::: "memory");        \
    __builtin_amdgcn_sched_barrier(0)

// Compute NR (8 or 7) rounds of the chunk at LDS byte base BOFF (0 or 16384).
// 16 pinned reads issued up front; round u waits only for its own pair
// (in-order DS completion): lgkmcnt(14-2u). Reads drain under VALU.
#define BODY(BOFF, NR)                                                        \
    {                                                                         \
        f32x4 a0, a1, a2, a3, a4, a5, a6, a7;                                 \
        f32x4 b0, b1, b2, b3, b4, b5, b6, b7;                                 \
        DSR(a0, (BOFF) + 0 * 2048); DSR(b0, (BOFF) + 0 * 2048 + 1024);        \
        DSR(a1, (BOFF) + 1 * 2048); DSR(b1, (BOFF) + 1 * 2048 + 1024);        \
        DSR(a2, (BOFF) + 2 * 2048); DSR(b2, (BOFF) + 2 * 2048 + 1024);        \
        DSR(a3, (BOFF) + 3 * 2048); DSR(b3, (BOFF) + 3 * 2048 + 1024);        \
        DSR(a4, (BOFF) + 4 * 2048); DSR(b4, (BOFF) + 4 * 2048 + 1024);        \
        DSR(a5, (BOFF) + 5 * 2048); DSR(b5, (BOFF) + 5 * 2048 + 1024);        \
        DSR(a6, (BOFF) + 6 * 2048); DSR(b6, (BOFF) + 6 * 2048 + 1024);        \
        DSR(a7, (BOFF) + 7 * 2048); DSR(b7, (BOFF) + 7 * 2048 + 1024);        \
        WAITL(14); ROUND(a0, b0)                                              \
        WAITL(12); ROUND(a1, b1)                                              \
        WAITL(10); ROUND(a2, b2)                                              \
        WAITL(8);  ROUND(a3, b3)                                              \
        WAITL(6);  ROUND(a4, b4)                                              \
        WAITL(4);  ROUND(a5, b5)                                              \
        WAITL(2);  ROUND(a6, b6)                                              \
        if ((NR) == 8) { WAITL(0); ROUND(a7, b7) }                            \
    }

// Stage chunk cix into buffer bix: this wave covers bytes [wave*4K, wave*4K+4K)
// of the 16KB chunk = 4 x 1KB global_load_lds.
#define STAGE(cix, bix)                                              \
    {                                                                \
        const char* g_ = gsrc + (size_t)(cix)*CHUNK_BYTES;           \
        char* l_ = lb + (bix)*CHUNK_BYTES;                           \
        _Pragma("unroll")                                            \
        for (int j = 0; j < 4; ++j)                                  \
            glds16(g_ + j * 1024, l_ + j * 1024);                    \
    }

#define WAITV(n) asm volatile("s_waitcnt vmcnt(" #n ")" ::: "memory")
#define BAR()                               \
    __builtin_amdgcn_s_barrier();           \
    __builtin_amdgcn_sched_barrier(0)

template <bool TAB>
__global__ __launch_bounds__(256, 1) void rotmat_main(const float* __restrict__ x,
                                                      const float* __restrict__ thetas,
                                                      const float2* __restrict__ cs,
                                                      float* __restrict__ out) {
    __shared__ f32x4 tab[2][CHUNK][2][64];  // [buf][round][plane][lane] = 32KB

    const int lane = threadIdx.x & 63;
    const int wave = threadIdx.x >> 6;
    const int col  = (blockIdx.x << 2) + wave;  // one column per wave
    const int k0   = lane << 2;                 // first pair index of this lane
    const bool is0 = (lane == 0);

    float lo[4], hi[4];
#pragma unroll
    for (int m = 0; m < 4; ++m) {
        lo[m] = x[(k0 + m) * N_COLS + col];
        hi[m] = x[(511 - k0 - m) * N_COLS + col];
    }

    if constexpr (TAB) {
        const char* gsrc = (const char*)cs + (size_t)wave * 4096 + (size_t)lane * 16;
        char* lb = (char*)(&tab[0][0][0][0]) + wave * 4096;
        unsigned lds_addr;
        {
            auto p3 = (__attribute__((address_space(3))) char*)(&tab[0][0][0][0]);
            lds_addr = (unsigned)(size_t)p3 + (unsigned)(lane * 16);
        }

        // Prologue: stage chunks 0,1; wait chunk 0 (and x loads); sync.
        STAGE(0, 0)
        STAGE(1, 1)
        WAITV(4);
        BAR();

        // 64 chunks of 8 rounds (512 incl. 1 pad round). Iteration t2 computes
        // chunks 2t2 (buf0), 2t2+1 (buf1); stages 2t2+2, 2t2+3. After compute:
        // barrier (reads drained inside BODY by the counted waits ending at
        // lgkmcnt(0)/(2)), stage over the just-used buffer, vmcnt(4)
        // (previous stage arrived), barrier.
        for (int t2 = 0; t2 < 31; ++t2) {
            BODY(0, 8)
            BAR();
            STAGE(2 * t2 + 2, 0)
            WAITV(4);
            BAR();
            BODY(16384, 8)
            BAR();
            STAGE(2 * t2 + 3, 1)
            WAITV(4);
            BAR();
        }
        // Chunk 62 (buf0); drain for chunk 63 (staged at t2=30).
        BODY(0, 8)
        WAITV(0);
        BAR();
        // Chunk 63: rounds 504..510 (7 real rounds; round 511 is pad; its 2
        // outstanding ds_reads write dead regs -- harmless).
        BODY(16384, 7)
    } else {
        // Fallback: compute schedule + sincos inline (no workspace table).
        int pu[4], pv[4];
#pragma unroll
        for (int m = 0; m < 4; ++m) {
            pu[m] = (k0 + m == 0) ? 0 : (k0 + m);
            pv[m] = 511 - (k0 + m);
        }
        for (int r = 0; r < 511; ++r) {
#pragma unroll
            for (int m = 0; m < 4; ++m) {
                int i = min(pu[m], pv[m]), j = max(pu[m], pv[m]);
                int t = i * 511 - (i * (i - 1)) / 2 + (j - i - 1);
                float s, c;
                sincosf(thetas[t], &s, &c);
                float sp = (pu[m] < pv[m]) ? s : -s;
                ROT(m, c, sp)
            }
            SHIFT()
#pragma unroll
            for (int m = 0; m < 4; ++m) {
                pu[m] = (k0 + m == 0) ? 0 : ((pu[m] == 1) ? 511 : pu[m] - 1);
                pv[m] = (pv[m] == 1) ? 511 : pv[m] - 1;
            }
        }
    }

    // After 511 shifts the position->row permutation is identity.
#pragma unroll
    for (int m = 0; m < 4; ++m) {
        out[(k0 + m) * N_COLS + col]       = lo[m];
        out[(511 - k0 - m) * N_COLS + col] = hi[m];
    }
}

extern "C" void kernel_launch(void* const* d_in, const int* in_sizes, int n_in,
                              void* d_out, int out_size, void* d_ws, size_t ws_size,
                              hipStream_t stream) {
    const float* x  = (const float*)d_in[0];
    const float* th = (const float*)d_in[1];
    float* out      = (float*)d_out;

    // Table: 512 rounds padded (chunk 63 stages pad round 511; never consumed).
    const size_t need = (size_t)512 * PAIRS * sizeof(float2);  // 1 MiB
    if (ws_size >= need) {
        float2* cs = (float2*)d_ws;
        rotmat_setup<<<511, PAIRS, 0, stream>>>(th, cs);
        rotmat_main<true><<<N_COLS / 4, 256, 0, stream>>>(x, th, cs, out);
    } else {
        rotmat_main<false><<<N_COLS / 4, 256, 0, stream>>>(x, th, nullptr, out);
    }
}